// Round 1
// baseline (639.504 us; speedup 1.0000x reference)
//
#include <hip/hip_runtime.h>
#include <math.h>

#define N_PTS   4096
#define RMAX    96
#define TILE    16
#define CHUNK   128
#define GP_JITTER 3e-7
#define PIV_TOL 5e-7

// ---------------------------------------------------------------------------
// Phase 1: pivoted Cholesky of the SE kernel matrix, K ~= V V^T  (rank<=RMAX)
// Single block, 1024 threads. fp64 math, fp32 storage of V (column-major:
// column k contiguous at V + k*N_PTS). Residual diagonal kept in fp64 LDS.
// ---------------------------------------------------------------------------
__global__ __launch_bounds__(1024) void pivchol_kernel(
    const float* __restrict__ t, const float* __restrict__ th_f,
    const float* __restrict__ th_l, float* __restrict__ V,
    int* __restrict__ meta)
{
    __shared__ float  ts[N_PTS];       // 16 KB
    __shared__ double dres[N_PTS];     // 32 KB
    __shared__ double red[1024];       // 8 KB
    __shared__ int    redi[1024];      // 4 KB
    __shared__ double pr[RMAX];        // pivot row V[j][p], j<k
    __shared__ double sh_dmax;
    __shared__ int    sh_p;

    const int tid = threadIdx.x;
    const double tf = (double)th_f[0];
    const double tl = (double)th_l[0];
    const double inv2l2 = 1.0 / (2.0 * tl * tl);

    for (int i = tid; i < N_PTS; i += 1024) { ts[i] = t[i]; dres[i] = tf; }
    __syncthreads();

    const int i0 = tid, i1 = tid + 1024, i2 = tid + 2048, i3 = tid + 3072;
    int r = RMAX;

    for (int k = 0; k < RMAX; ++k) {
        // ---- argmax of residual diagonal ----
        double m = dres[i0]; int mi = i0;
        if (dres[i1] > m) { m = dres[i1]; mi = i1; }
        if (dres[i2] > m) { m = dres[i2]; mi = i2; }
        if (dres[i3] > m) { m = dres[i3]; mi = i3; }
        red[tid] = m; redi[tid] = mi;
        __syncthreads();
        for (int s = 512; s >= 64; s >>= 1) {
            if (tid < s && red[tid + s] > red[tid]) {
                red[tid] = red[tid + s]; redi[tid] = redi[tid + s];
            }
            __syncthreads();
        }
        if (tid < 64) {   // wave 0 finishes without barriers
            m = red[tid]; mi = redi[tid];
            for (int s = 32; s > 0; s >>= 1) {
                double om = __shfl_down(m, s);
                int    oi = __shfl_down(mi, s);
                if (om > m) { m = om; mi = oi; }
            }
            if (tid == 0) { sh_dmax = m; sh_p = mi; }
        }
        __syncthreads();
        const double dmax = sh_dmax;
        const int p = sh_p;
        if (dmax < PIV_TOL) { r = k; break; }   // uniform across block

        // ---- gather pivot row of V into LDS ----
        for (int j = tid; j < k; j += 1024) pr[j] = (double)V[j * N_PTS + p];
        __syncthreads();

        // ---- compute column k ----
        const double tp  = (double)ts[p];
        const double isq = 1.0 / sqrt(dmax);
        double e0 = (double)ts[i0] - tp;
        double e1 = (double)ts[i1] - tp;
        double e2 = (double)ts[i2] - tp;
        double e3 = (double)ts[i3] - tp;
        double a0 = tf * exp(-e0 * e0 * inv2l2);
        double a1 = tf * exp(-e1 * e1 * inv2l2);
        double a2 = tf * exp(-e2 * e2 * inv2l2);
        double a3 = tf * exp(-e3 * e3 * inv2l2);
        for (int j = 0; j < k; ++j) {
            const double pj = pr[j];
            const float* col = V + j * N_PTS;
            a0 -= (double)col[i0] * pj;
            a1 -= (double)col[i1] * pj;
            a2 -= (double)col[i2] * pj;
            a3 -= (double)col[i3] * pj;
        }
        const float f0 = (float)(a0 * isq);
        const float f1 = (float)(a1 * isq);
        const float f2 = (float)(a2 * isq);
        const float f3 = (float)(a3 * isq);
        float* ck = V + k * N_PTS;
        ck[i0] = f0; ck[i1] = f1; ck[i2] = f2; ck[i3] = f3;
        dres[i0] = (i0 == p) ? 0.0 : dres[i0] - (double)f0 * (double)f0;
        dres[i1] = (i1 == p) ? 0.0 : dres[i1] - (double)f1 * (double)f1;
        dres[i2] = (i2 == p) ? 0.0 : dres[i2] - (double)f2 * (double)f2;
        dres[i3] = (i3 == p) ? 0.0 : dres[i3] - (double)f3 * (double)f3;
        __syncthreads();
    }
    if (tid == 0) meta[0] = r;
}

// ---------------------------------------------------------------------------
// Phase 2: C = noise*I + V^T V   (RMAX x RMAX, fp64 accumulate)
// Grid (RMAX/TILE)^2, 256 threads. Columns >= r_eff treated as zero.
// ---------------------------------------------------------------------------
__global__ __launch_bounds__(256) void gram_kernel(
    const float* __restrict__ V, const int* __restrict__ meta,
    const float* __restrict__ th_n, double* __restrict__ C)
{
    __shared__ float sA[TILE][CHUNK + 1];
    __shared__ float sB[TILE][CHUNK + 1];
    const int r = meta[0];
    const int ka0 = blockIdx.y * TILE;
    const int kb0 = blockIdx.x * TILE;
    const int tid = threadIdx.x;
    const int a = tid / TILE, b = tid % TILE;

    double acc = 0.0;
    for (int base = 0; base < N_PTS; base += CHUNK) {
        for (int l = tid; l < TILE * CHUNK; l += 256) {
            const int c = l / CHUNK, ii = l % CHUNK;
            sA[c][ii] = (ka0 + c < r) ? V[(ka0 + c) * N_PTS + base + ii] : 0.0f;
            sB[c][ii] = (kb0 + c < r) ? V[(kb0 + c) * N_PTS + base + ii] : 0.0f;
        }
        __syncthreads();
        for (int ii = 0; ii < CHUNK; ++ii)
            acc += (double)sA[a][ii] * (double)sB[b][ii];
        __syncthreads();
    }
    const int ga = ka0 + a, gb = kb0 + b;
    const double tn = (double)th_n[0];
    const double noise = GP_JITTER + tn * tn;
    C[ga * RMAX + gb] = acc + (ga == gb ? noise : 0.0);
}

// ---------------------------------------------------------------------------
// Phase 3: w[k][d] = V[:,k] . traj[d,:]   and   yy[d] = ||traj[d,:]||^2
// Grid RMAX+1 blocks, 256 threads.
// ---------------------------------------------------------------------------
__global__ __launch_bounds__(256) void proj_kernel(
    const float* __restrict__ V, const float* __restrict__ traj,
    const int* __restrict__ meta, double* __restrict__ w,
    double* __restrict__ yy)
{
    __shared__ double red[4][256];
    const int k = blockIdx.x;
    const int tid = threadIdx.x;
    const int r = meta[0];
    double a0 = 0, a1 = 0, a2 = 0, a3 = 0;
    if (k < RMAX) {
        if (k < r) {
            const float* col = V + (size_t)k * N_PTS;
            for (int i = tid; i < N_PTS; i += 256) {
                const double v = (double)col[i];
                a0 += v * (double)traj[i];
                a1 += v * (double)traj[N_PTS + i];
                a2 += v * (double)traj[2 * N_PTS + i];
                a3 += v * (double)traj[3 * N_PTS + i];
            }
        }
    } else {
        for (int i = tid; i < N_PTS; i += 256) {
            const double y0 = traj[i],            y1 = traj[N_PTS + i];
            const double y2 = traj[2 * N_PTS + i], y3 = traj[3 * N_PTS + i];
            a0 += y0 * y0; a1 += y1 * y1; a2 += y2 * y2; a3 += y3 * y3;
        }
    }
    red[0][tid] = a0; red[1][tid] = a1; red[2][tid] = a2; red[3][tid] = a3;
    __syncthreads();
    for (int s = 128; s > 0; s >>= 1) {
        if (tid < s) {
            red[0][tid] += red[0][tid + s];
            red[1][tid] += red[1][tid + s];
            red[2][tid] += red[2][tid + s];
            red[3][tid] += red[3][tid + s];
        }
        __syncthreads();
    }
    if (tid == 0) {
        if (k < RMAX) {
            w[k * 4 + 0] = red[0][0]; w[k * 4 + 1] = red[1][0];
            w[k * 4 + 2] = red[2][0]; w[k * 4 + 3] = red[3][0];
        } else {
            yy[0] = red[0][0]; yy[1] = red[1][0];
            yy[2] = red[2][0]; yy[3] = red[3][0];
        }
    }
}

// ---------------------------------------------------------------------------
// Phase 4: in-place Cholesky of C (fp64, RMAX x RMAX in global, L2-resident),
// single block; also logdet(C).
// ---------------------------------------------------------------------------
__global__ __launch_bounds__(256) void chol_small_kernel(
    double* __restrict__ C, double* __restrict__ logdetC)
{
    __shared__ double sh_inv;
    __shared__ double sh_ld;
    const int tid = threadIdx.x;
    if (tid == 0) sh_ld = 0.0;
    __syncthreads();
    for (int j = 0; j < RMAX; ++j) {
        if (tid == 0) {
            const double v = sqrt(C[j * RMAX + j]);
            C[j * RMAX + j] = v;
            sh_ld += 2.0 * log(v);
            sh_inv = 1.0 / v;
        }
        __syncthreads();
        const double inv = sh_inv;
        for (int i = j + 1 + tid; i < RMAX; i += 256) C[i * RMAX + j] *= inv;
        __syncthreads();
        const int rem = RMAX - 1 - j;              // rows strictly below j
        const int T = rem * (rem + 1) / 2;         // lower-tri pairs (i>=kk)
        for (int f = tid; f < T; f += 256) {
            int mrow = (int)((sqrt(8.0 * (double)f + 1.0) - 1.0) * 0.5);
            while ((mrow + 1) * (mrow + 2) / 2 <= f) ++mrow;
            while (mrow * (mrow + 1) / 2 > f) --mrow;
            const int c = f - mrow * (mrow + 1) / 2;
            const int i = j + 1 + mrow, kk = j + 1 + c;
            C[i * RMAX + kk] -= C[i * RMAX + j] * C[kk * RMAX + j];
        }
        __syncthreads();
    }
    if (tid == 0) logdetC[0] = sh_ld;
}

// ---------------------------------------------------------------------------
// Phase 5: forward solve L u = w (4 RHS); w.z = ||u||^2 (z = C^{-1}w).
// quad_d = (yy_d - sum_k u[k][d]^2)/noise ;  assemble lml, write fp32 out.
// ---------------------------------------------------------------------------
__global__ __launch_bounds__(256) void solve_final_kernel(
    const double* __restrict__ C, const double* __restrict__ w,
    const double* __restrict__ yy, const double* __restrict__ ldC,
    const float* __restrict__ th_n, const int* __restrict__ n_in,
    float* __restrict__ out)
{
    __shared__ double u[RMAX][4];
    __shared__ double red[256];
    const int tid = threadIdx.x;
    for (int l = tid; l < RMAX * 4; l += 256) u[l >> 2][l & 3] = w[l];
    __syncthreads();
    for (int j = 0; j < RMAX; ++j) {
        if (tid < 4) u[j][tid] /= C[j * RMAX + j];
        __syncthreads();
        const double uj0 = u[j][0], uj1 = u[j][1], uj2 = u[j][2], uj3 = u[j][3];
        for (int i = j + 1 + tid; i < RMAX; i += 256) {
            const double lij = C[i * RMAX + j];
            u[i][0] -= lij * uj0; u[i][1] -= lij * uj1;
            u[i][2] -= lij * uj2; u[i][3] -= lij * uj3;
        }
        __syncthreads();
    }
    double loc = 0.0;
    for (int l = tid; l < RMAX * 4; l += 256) {
        const double v = u[l >> 2][l & 3];
        loc += v * v;
    }
    red[tid] = loc;
    __syncthreads();
    for (int s = 128; s > 0; s >>= 1) {
        if (tid < s) red[tid] += red[tid + s];
        __syncthreads();
    }
    if (tid == 0) {
        const double tn = (double)th_n[0];
        const double noise = GP_JITTER + tn * tn;
        const double sumyy = yy[0] + yy[1] + yy[2] + yy[3];
        const double quad = (sumyy - red[0]) / noise;
        const double logdetA = (double)(N_PTS - RMAX) * log(noise) + ldC[0];
        const double lml = 0.5 * quad + 0.5 * logdetA
                         + 0.5 * (double)n_in[0] * log(6.283185307179586);
        out[0] = (float)lml;
    }
}

extern "C" void kernel_launch(void* const* d_in, const int* in_sizes, int n_in,
                              void* d_out, int out_size, void* d_ws, size_t ws_size,
                              hipStream_t stream) {
    const float* traj = (const float*)d_in[0];   // [4, 4096]
    const float* t    = (const float*)d_in[1];   // [4096]
    const float* thf  = (const float*)d_in[2];
    const float* thl  = (const float*)d_in[3];
    const float* thn  = (const float*)d_in[4];
    const int*   nn   = (const int*)d_in[5];
    float* out = (float*)d_out;

    char* ws = (char*)d_ws;
    float* V = (float*)ws;                                   // RMAX*N floats (1.5 MB)
    size_t off = (size_t)RMAX * N_PTS * sizeof(float);
    int* meta = (int*)(ws + off);                 off += 64; // keep 8B alignment
    double* C   = (double*)(ws + off);            off += (size_t)RMAX * RMAX * sizeof(double);
    double* w   = (double*)(ws + off);            off += (size_t)RMAX * 4 * sizeof(double);
    double* yy  = (double*)(ws + off);            off += 4 * sizeof(double);
    double* ldC = (double*)(ws + off);            off += sizeof(double);

    pivchol_kernel<<<1, 1024, 0, stream>>>(t, thf, thl, V, meta);
    gram_kernel<<<dim3(RMAX / TILE, RMAX / TILE), 256, 0, stream>>>(V, meta, thn, C);
    proj_kernel<<<RMAX + 1, 256, 0, stream>>>(V, traj, meta, w, yy);
    chol_small_kernel<<<1, 256, 0, stream>>>(C, ldC);
    solve_final_kernel<<<1, 256, 0, stream>>>(C, w, yy, ldC, thn, nn, out);
}

// Round 2
// 376.777 us; speedup vs baseline: 1.6973x; 1.6973x over previous
//
#include <hip/hip_runtime.h>
#include <math.h>

#define N_PTS   4096
#define RMAX    96
#define TILE    16
#define CHUNK   128
#define VCACHE  8
#define GP_JITTER 3e-7
#define PIV_TOL 5e-7

// ---------------------------------------------------------------------------
// Phase 1: pivoted Cholesky of the SE kernel matrix, K ~= V V^T  (rank<=RMAX)
// Single block, 1024 threads. Residual diag in REGISTERS (4/thread), argmax
// via wave shuffles (3 barriers/step), fp32 inner math, first VCACHE columns
// of V cached in LDS to cut L2 re-reads.
// ---------------------------------------------------------------------------
__global__ __launch_bounds__(1024) void pivchol_kernel(
    const float* __restrict__ t, const float* __restrict__ th_f,
    const float* __restrict__ th_l, float* __restrict__ V,
    int* __restrict__ meta)
{
    __shared__ float  ts[N_PTS];            // 16 KB
    __shared__ float  vc[VCACHE][N_PTS];    // 128 KB column cache
    __shared__ float  pr[RMAX];             // pivot row V[j][p], j<k
    __shared__ double redv[16];
    __shared__ int    redi[16];
    __shared__ double sh_dmax;
    __shared__ int    sh_p;

    const int tid = threadIdx.x;
    const float tf = th_f[0];
    const float tl = th_l[0];
    const float inv2l2 = 1.0f / (2.0f * tl * tl);

    for (int i = tid; i < N_PTS; i += 1024) ts[i] = t[i];
    __syncthreads();

    const int i0 = tid, i1 = tid + 1024, i2 = tid + 2048, i3 = tid + 3072;
    double d0 = (double)tf, d1 = (double)tf, d2 = (double)tf, d3 = (double)tf;
    int r = RMAX;

    for (int k = 0; k < RMAX; ++k) {
        // ---- argmax of residual diagonal (regs -> wave shuffle -> LDS) ----
        double m = d0; int mi = i0;
        if (d1 > m) { m = d1; mi = i1; }
        if (d2 > m) { m = d2; mi = i2; }
        if (d3 > m) { m = d3; mi = i3; }
        #pragma unroll
        for (int s = 32; s > 0; s >>= 1) {
            double om = __shfl_down(m, s);
            int    oi = __shfl_down(mi, s);
            if (om > m) { m = om; mi = oi; }
        }
        if ((tid & 63) == 0) { redv[tid >> 6] = m; redi[tid >> 6] = mi; }
        __syncthreads();                                        // B1
        if (tid < 64) {
            double m2 = (tid < 16) ? redv[tid] : -1.0;
            int    mi2 = (tid < 16) ? redi[tid] : 0;
            #pragma unroll
            for (int s = 8; s > 0; s >>= 1) {
                double om = __shfl_down(m2, s);
                int    oi = __shfl_down(mi2, s);
                if (om > m2) { m2 = om; mi2 = oi; }
            }
            if (tid == 0) { sh_dmax = m2; sh_p = mi2; }
        }
        __syncthreads();                                        // B2
        const double dmax = sh_dmax;
        const int p = sh_p;
        if (dmax < PIV_TOL) { r = k; break; }   // uniform across block

        // ---- gather pivot row of V ----
        if (tid < k) pr[tid] = (tid < VCACHE) ? vc[tid][p] : V[tid * N_PTS + p];
        __syncthreads();                                        // B3

        // ---- compute column k (fp32) ----
        const float tp  = ts[p];
        const float isq = (float)(1.0 / sqrt(dmax));
        float e, a0, a1, a2, a3;
        e = ts[i0] - tp; a0 = tf * __expf(-e * e * inv2l2);
        e = ts[i1] - tp; a1 = tf * __expf(-e * e * inv2l2);
        e = ts[i2] - tp; a2 = tf * __expf(-e * e * inv2l2);
        e = ts[i3] - tp; a3 = tf * __expf(-e * e * inv2l2);
        const int kc = (k < VCACHE) ? k : VCACHE;
        for (int j = 0; j < kc; ++j) {           // cached columns
            const float pj = pr[j];
            a0 -= vc[j][i0] * pj;
            a1 -= vc[j][i1] * pj;
            a2 -= vc[j][i2] * pj;
            a3 -= vc[j][i3] * pj;
        }
        for (int j = VCACHE; j < k; ++j) {       // L2-resident columns
            const float pj = pr[j];
            const float* col = V + j * N_PTS;
            a0 -= col[i0] * pj;
            a1 -= col[i1] * pj;
            a2 -= col[i2] * pj;
            a3 -= col[i3] * pj;
        }
        const float f0 = a0 * isq, f1 = a1 * isq, f2 = a2 * isq, f3 = a3 * isq;
        float* ck = V + k * N_PTS;
        ck[i0] = f0; ck[i1] = f1; ck[i2] = f2; ck[i3] = f3;
        if (k < VCACHE) {
            vc[k][i0] = f0; vc[k][i1] = f1; vc[k][i2] = f2; vc[k][i3] = f3;
        }
        d0 = (i0 == p) ? 0.0 : d0 - (double)f0 * (double)f0;
        d1 = (i1 == p) ? 0.0 : d1 - (double)f1 * (double)f1;
        d2 = (i2 == p) ? 0.0 : d2 - (double)f2 * (double)f2;
        d3 = (i3 == p) ? 0.0 : d3 - (double)f3 * (double)f3;
        // no barrier needed: residual diag is register-private; V col k write
        // is ordered by B1/B2 of the next iteration before anyone reads it.
    }
    if (tid == 0) meta[0] = r;
}

// ---------------------------------------------------------------------------
// Phase 2: C = noise*I + V^T V   (RMAX x RMAX, fp64 accumulate)
// Tiles fully outside [0,r) skip the sweep entirely (product is zero).
// ---------------------------------------------------------------------------
__global__ __launch_bounds__(256) void gram_kernel(
    const float* __restrict__ V, const int* __restrict__ meta,
    const float* __restrict__ th_n, double* __restrict__ C)
{
    __shared__ float sA[TILE][CHUNK + 1];
    __shared__ float sB[TILE][CHUNK + 1];
    const int r = meta[0];
    const int ka0 = blockIdx.y * TILE;
    const int kb0 = blockIdx.x * TILE;
    const int tid = threadIdx.x;
    const int a = tid / TILE, b = tid % TILE;

    double acc = 0.0;
    if (ka0 < r && kb0 < r) {
        for (int base = 0; base < N_PTS; base += CHUNK) {
            for (int l = tid; l < TILE * CHUNK; l += 256) {
                const int c = l / CHUNK, ii = l % CHUNK;
                sA[c][ii] = (ka0 + c < r) ? V[(ka0 + c) * N_PTS + base + ii] : 0.0f;
                sB[c][ii] = (kb0 + c < r) ? V[(kb0 + c) * N_PTS + base + ii] : 0.0f;
            }
            __syncthreads();
            for (int ii = 0; ii < CHUNK; ++ii)
                acc += (double)sA[a][ii] * (double)sB[b][ii];
            __syncthreads();
        }
    }
    const int ga = ka0 + a, gb = kb0 + b;
    const double tn = (double)th_n[0];
    const double noise = GP_JITTER + tn * tn;
    C[ga * RMAX + gb] = acc + (ga == gb ? noise : 0.0);
}

// ---------------------------------------------------------------------------
// Phase 3: w[k][d] = V[:,k] . traj[d,:]   and   yy[d] = ||traj[d,:]||^2
// ---------------------------------------------------------------------------
__global__ __launch_bounds__(256) void proj_kernel(
    const float* __restrict__ V, const float* __restrict__ traj,
    const int* __restrict__ meta, double* __restrict__ w,
    double* __restrict__ yy)
{
    __shared__ double red[4][256];
    const int k = blockIdx.x;
    const int tid = threadIdx.x;
    const int r = meta[0];
    double a0 = 0, a1 = 0, a2 = 0, a3 = 0;
    if (k < RMAX) {
        if (k < r) {
            const float* col = V + (size_t)k * N_PTS;
            for (int i = tid; i < N_PTS; i += 256) {
                const double v = (double)col[i];
                a0 += v * (double)traj[i];
                a1 += v * (double)traj[N_PTS + i];
                a2 += v * (double)traj[2 * N_PTS + i];
                a3 += v * (double)traj[3 * N_PTS + i];
            }
        }
    } else {
        for (int i = tid; i < N_PTS; i += 256) {
            const double y0 = traj[i],             y1 = traj[N_PTS + i];
            const double y2 = traj[2 * N_PTS + i], y3 = traj[3 * N_PTS + i];
            a0 += y0 * y0; a1 += y1 * y1; a2 += y2 * y2; a3 += y3 * y3;
        }
    }
    red[0][tid] = a0; red[1][tid] = a1; red[2][tid] = a2; red[3][tid] = a3;
    __syncthreads();
    for (int s = 128; s > 0; s >>= 1) {
        if (tid < s) {
            red[0][tid] += red[0][tid + s];
            red[1][tid] += red[1][tid + s];
            red[2][tid] += red[2][tid + s];
            red[3][tid] += red[3][tid + s];
        }
        __syncthreads();
    }
    if (tid == 0) {
        if (k < RMAX) {
            w[k * 4 + 0] = red[0][0]; w[k * 4 + 1] = red[1][0];
            w[k * 4 + 2] = red[2][0]; w[k * 4 + 3] = red[3][0];
        } else {
            yy[0] = red[0][0]; yy[1] = red[1][0];
            yy[2] = red[2][0]; yy[3] = red[3][0];
        }
    }
}

// ---------------------------------------------------------------------------
// Phases 4+5 fused, fully LDS-resident: Cholesky of C (r x r, stride-97 pad),
// logdet, forward solve L u = w (4 RHS), quad, final lml. Single block, 256 thr.
// ---------------------------------------------------------------------------
__global__ __launch_bounds__(256) void chol_solve_kernel(
    const double* __restrict__ C, const double* __restrict__ w,
    const double* __restrict__ yy, const int* __restrict__ meta,
    const float* __restrict__ th_n, const int* __restrict__ n_in,
    float* __restrict__ out)
{
    __shared__ double sC[RMAX * 97];   // 74.5 KB
    __shared__ double su[RMAX][4];
    __shared__ double red[256], red2[256];
    __shared__ double sh_inv;
    const int tid = threadIdx.x;
    const int r = meta[0];

    for (int l = tid; l < r * r; l += 256) {
        const int i = l / r, j = l % r;
        sC[i * 97 + j] = C[i * RMAX + j];
    }
    for (int l = tid; l < r * 4; l += 256) su[l >> 2][l & 3] = w[l];
    __syncthreads();

    // ---- Cholesky, row-per-thread trailing update ----
    for (int j = 0; j < r; ++j) {
        if (tid == 0) {
            const double d = sqrt(sC[j * 97 + j]);
            sC[j * 97 + j] = d;
            sh_inv = 1.0 / d;
        }
        __syncthreads();
        const int i = j + 1 + tid;
        double lij = 0.0;
        if (i < r) { lij = sC[i * 97 + j] * sh_inv; sC[i * 97 + j] = lij; }
        __syncthreads();
        if (i < r) {
            for (int kk = j + 1; kk <= i; ++kk)
                sC[i * 97 + kk] -= lij * sC[kk * 97 + j];   // broadcast read
        }
        __syncthreads();
    }

    double ld = (tid < r) ? 2.0 * log(sC[tid * 97 + tid]) : 0.0;

    // ---- forward solve L u = w, 4 RHS ----
    for (int j = 0; j < r; ++j) {
        if (tid < 4) su[j][tid] /= sC[j * 97 + j];
        __syncthreads();
        const int i = j + 1 + tid;
        if (i < r) {
            const double lij = sC[i * 97 + j];
            su[i][0] -= lij * su[j][0]; su[i][1] -= lij * su[j][1];
            su[i][2] -= lij * su[j][2]; su[i][3] -= lij * su[j][3];
        }
        __syncthreads();
    }

    double q = 0.0;
    for (int l = tid; l < r * 4; l += 256) {
        const double v = su[l >> 2][l & 3];
        q += v * v;
    }
    red[tid] = ld; red2[tid] = q;
    __syncthreads();
    for (int s = 128; s > 0; s >>= 1) {
        if (tid < s) { red[tid] += red[tid + s]; red2[tid] += red2[tid + s]; }
        __syncthreads();
    }
    if (tid == 0) {
        const double tn = (double)th_n[0];
        const double noise = GP_JITTER + tn * tn;
        const double sumyy = yy[0] + yy[1] + yy[2] + yy[3];
        const double quad = (sumyy - red2[0]) / noise;
        const double logdetA = (double)(N_PTS - r) * log(noise) + red[0];
        const double lml = 0.5 * quad + 0.5 * logdetA
                         + 0.5 * (double)n_in[0] * log(6.283185307179586);
        out[0] = (float)lml;
    }
}

extern "C" void kernel_launch(void* const* d_in, const int* in_sizes, int n_in,
                              void* d_out, int out_size, void* d_ws, size_t ws_size,
                              hipStream_t stream) {
    const float* traj = (const float*)d_in[0];   // [4, 4096]
    const float* t    = (const float*)d_in[1];   // [4096]
    const float* thf  = (const float*)d_in[2];
    const float* thl  = (const float*)d_in[3];
    const float* thn  = (const float*)d_in[4];
    const int*   nn   = (const int*)d_in[5];
    float* out = (float*)d_out;

    char* ws = (char*)d_ws;
    float* V = (float*)ws;                                   // RMAX*N floats (1.5 MB)
    size_t off = (size_t)RMAX * N_PTS * sizeof(float);
    int* meta = (int*)(ws + off);                 off += 64;
    double* C   = (double*)(ws + off);            off += (size_t)RMAX * RMAX * sizeof(double);
    double* w   = (double*)(ws + off);            off += (size_t)RMAX * 4 * sizeof(double);
    double* yy  = (double*)(ws + off);            off += 4 * sizeof(double);

    pivchol_kernel<<<1, 1024, 0, stream>>>(t, thf, thl, V, meta);
    gram_kernel<<<dim3(RMAX / TILE, RMAX / TILE), 256, 0, stream>>>(V, meta, thn, C);
    proj_kernel<<<RMAX + 1, 256, 0, stream>>>(V, traj, meta, w, yy);
    chol_solve_kernel<<<1, 256, 0, stream>>>(C, w, yy, meta, thn, nn, out);
}

// Round 4
// 370.998 us; speedup vs baseline: 1.7237x; 1.0156x over previous
//
#include <hip/hip_runtime.h>
#include <math.h>

#define N_PTS  4096
#define MPIV   96
#define NSEG   32
#define SEG    128            // N_PTS / NSEG
#define GP_JITTER 3e-7
#define DELTA_FRAC 3e-5       // regularizer on K_PP, scaled by theta_f
#define NZERO (MPIV * MPIV + MPIV * 4 + 4)

__device__ __forceinline__ int piv_idx(int j) {
    return (j * N_PTS) / MPIV + N_PTS / (2 * MPIV);   // evenly spaced (t sorted)
}

// ---------------------------------------------------------------------------
// Kernel 0: zero the fp64 accumulators (G | b | yy contiguous). ws is
// re-poisoned to 0xAA before every launch, so this must run each call.
// ---------------------------------------------------------------------------
__global__ __launch_bounds__(256) void zero_kernel(double* __restrict__ z) {
    for (int i = blockIdx.x * 256 + threadIdx.x; i < NZERO; i += gridDim.x * 256)
        z[i] = 0.0;
}

// ---------------------------------------------------------------------------
// Kernel 1: per-segment G = U^T U (fp64 acc, 6x6 register tile -> 36
// independent accumulators), b = U^T y (fp64), yy = ||y||^2 (fp64).
// U built on the fly in LDS (fp32). Partials folded with atomicAdd(double)
// -- G is then the near-exact Gram of the stored fp32 U => PSD guaranteed.
// ---------------------------------------------------------------------------
__global__ __launch_bounds__(256) void gram_fused_kernel(
    const float* __restrict__ t, const float* __restrict__ traj,
    const float* __restrict__ thf, const float* __restrict__ thl,
    double* __restrict__ G, double* __restrict__ b, double* __restrict__ yy)
{
    __shared__ float sU[MPIV][SEG + 1];   // 96 x 129 fp32 = 49.5 KB
    __shared__ float st[SEG];
    __shared__ float stp[MPIV];
    __shared__ float sy[4][SEG];

    const int seg = blockIdx.x, tid = threadIdx.x;
    const int ibase = seg * SEG;
    const float tf = thf[0], tl = thl[0];
    const float inv2l2 = 1.0f / (2.0f * tl * tl);

    if (tid < SEG)  st[tid]  = t[ibase + tid];
    if (tid < MPIV) stp[tid] = t[piv_idx(tid)];
    for (int l = tid; l < 4 * SEG; l += 256) {
        const int d = l >> 7, ii = l & (SEG - 1);
        sy[d][ii] = traj[d * N_PTS + ibase + ii];
    }
    __syncthreads();

    for (int l = tid; l < MPIV * SEG; l += 256) {
        const int j = l >> 7, ii = l & (SEG - 1);
        const float e = st[ii] - stp[j];
        sU[j][ii] = tf * __expf(-e * e * inv2l2);
    }
    __syncthreads();

    // ---- G tile: thread (ta,tb) owns rows a0..a0+5 x cols b0..b0+5 ----
    const int ta = tid >> 4, tb = tid & 15;
    const int a0 = ta * 6, b0 = tb * 6;
    double acc[6][6];
    #pragma unroll
    for (int d = 0; d < 6; ++d)
        #pragma unroll
        for (int e = 0; e < 6; ++e) acc[d][e] = 0.0;

    for (int ii = 0; ii < SEG; ++ii) {
        double va[6], vb[6];
        #pragma unroll
        for (int d = 0; d < 6; ++d) va[d] = (double)sU[a0 + d][ii];
        #pragma unroll
        for (int e = 0; e < 6; ++e) vb[e] = (double)sU[b0 + e][ii];
        #pragma unroll
        for (int d = 0; d < 6; ++d)
            #pragma unroll
            for (int e = 0; e < 6; ++e) acc[d][e] += va[d] * vb[e];
    }
    #pragma unroll
    for (int d = 0; d < 6; ++d)
        #pragma unroll
        for (int e = 0; e < 6; ++e)
            atomicAdd(&G[(a0 + d) * MPIV + (b0 + e)], acc[d][e]);

    // ---- b and yy partials (fp64) ----
    if (tid < MPIV) {
        double s0 = 0, s1 = 0, s2 = 0, s3 = 0;
        for (int ii = 0; ii < SEG; ++ii) {
            const double u = (double)sU[tid][ii];
            s0 += u * (double)sy[0][ii];
            s1 += u * (double)sy[1][ii];
            s2 += u * (double)sy[2][ii];
            s3 += u * (double)sy[3][ii];
        }
        atomicAdd(&b[tid * 4 + 0], s0);
        atomicAdd(&b[tid * 4 + 1], s1);
        atomicAdd(&b[tid * 4 + 2], s2);
        atomicAdd(&b[tid * 4 + 3], s3);
    } else if (tid < MPIV + 4) {
        const int d = tid - MPIV;
        double s = 0;
        for (int ii = 0; ii < SEG; ++ii) {
            const double v = (double)sy[d][ii];
            s += v * v;
        }
        atomicAdd(&yy[d], s);
    }
}

// ---------------------------------------------------------------------------
// Kernel 2: everything small, one block, LDS-resident fp64.
//  B  = K_PP + delta*I  -> chol -> logdet(B)
//  M~ = noise*B + G     -> chol -> logdet(M~), solve L u = b
// Interleaved software-pipelined Choleskys: one barrier per column.
//  lml = 0.5*(sum_yy - ||u||^2)/noise + 0.5*[(N-m)log(noise)+ldM-ldB]
//        + 0.5*n*log(2pi)
// ---------------------------------------------------------------------------
__global__ __launch_bounds__(256) void final_kernel(
    const float* __restrict__ t, const float* __restrict__ thf,
    const float* __restrict__ thl, const float* __restrict__ thn,
    const int* __restrict__ nin, const double* __restrict__ G,
    const double* __restrict__ b, const double* __restrict__ yy,
    float* __restrict__ out)
{
    __shared__ double sB[MPIV][MPIV + 1];   // 72.75 KB
    __shared__ double sM[MPIV][MPIV + 1];   // 72.75 KB
    __shared__ double colB[2][MPIV], colM[2][MPIV];
    __shared__ double su[MPIV][4], ub[MPIV][4];
    __shared__ double sinvB[2], sinvM[2];
    __shared__ double redsm[3][4];
    __shared__ float  stp[MPIV];

    const int tid = threadIdx.x;
    const double tf = (double)thf[0], tl = (double)thl[0], tn = (double)thn[0];
    const double inv2l2 = 1.0 / (2.0 * tl * tl);
    const double noise = GP_JITTER + tn * tn;
    const double delta = DELTA_FRAC * tf;
    const double floorB = 1e-3 * delta;           // graceful-degradation clamps
    const double floorM = 1e-3 * noise * delta;

    if (tid < MPIV) stp[tid] = t[piv_idx(tid)];
    __syncthreads();

    for (int l = tid; l < MPIV * MPIV; l += 256) {
        const int i = l / MPIV, j = l % MPIV;
        const double e = (double)stp[i] - (double)stp[j];
        const double kv = tf * exp(-e * e * inv2l2) + (i == j ? delta : 0.0);
        sB[i][j] = kv;
        sM[i][j] = noise * kv + G[l];
    }
    for (int l = tid; l < MPIV * 4; l += 256) su[l >> 2][l & 3] = b[l];
    __syncthreads();

    // ---- interleaved pipelined Cholesky of sB and sM ----
    double ldB = 0.0, ldM = 0.0;
    if (tid == 0) {
        double d = sqrt(sB[0][0]); sB[0][0] = d; sinvB[0] = 1.0 / d; ldB += 2.0 * log(d);
        d = sqrt(sM[0][0]);        sM[0][0] = d; sinvM[0] = 1.0 / d; ldM += 2.0 * log(d);
    }
    __syncthreads();
    for (int j = 0; j < MPIV - 1; ++j) {
        const int par = j & 1, npar = par ^ 1;
        if (tid > j && tid < MPIV) {
            const double lB = sB[tid][j] * sinvB[par]; colB[par][tid] = lB; sB[tid][j] = lB;
            const double lM = sM[tid][j] * sinvM[par]; colM[par][tid] = lM; sM[tid][j] = lM;
            if (tid == j + 1) {   // pipelined next diagonal
                double d2 = sB[tid][tid] - lB * lB; d2 = d2 > floorB ? d2 : floorB;
                double d = sqrt(d2); sB[tid][tid] = d; sinvB[npar] = 1.0 / d; ldB += 2.0 * log(d);
                d2 = sM[tid][tid] - lM * lM; d2 = d2 > floorM ? d2 : floorM;
                d = sqrt(d2); sM[tid][tid] = d; sinvM[npar] = 1.0 / d; ldM += 2.0 * log(d);
            }
        }
        __syncthreads();   // the ONLY barrier per column
        if (tid >= j + 2 && tid < MPIV) {   // row-owner trailing update
            const double lB = colB[par][tid], lM = colM[par][tid];
            for (int kk = j + 1; kk <= tid; ++kk) {
                sB[tid][kk] -= lB * colB[par][kk];
                sM[tid][kk] -= lM * colM[par][kk];
            }
        }
        // no barrier: all colB[par] reads precede the next barrier; colB[par]
        // is next written two iterations later, after that barrier.
    }

    // ---- pipelined forward solve  L_M u = b  (4 RHS) ----
    if (tid == 0) {
        const double inv = 1.0 / sM[0][0];
        #pragma unroll
        for (int d = 0; d < 4; ++d) ub[0][d] = su[0][d] * inv;
    }
    __syncthreads();
    for (int j = 0; j < MPIV - 1; ++j) {
        if (tid > j && tid < MPIV) {
            const double lij = sM[tid][j];
            su[tid][0] -= lij * ub[j][0]; su[tid][1] -= lij * ub[j][1];
            su[tid][2] -= lij * ub[j][2]; su[tid][3] -= lij * ub[j][3];
            if (tid == j + 1) {
                const double inv = 1.0 / sM[tid][tid];
                #pragma unroll
                for (int d = 0; d < 4; ++d) ub[tid][d] = su[tid][d] * inv;
            }
        }
        __syncthreads();
    }

    // ---- reductions (wave shuffles) + final assembly ----
    double q = 0.0;
    if (tid < MPIV) {
        #pragma unroll
        for (int d = 0; d < 4; ++d) q += ub[tid][d] * ub[tid][d];
    }
    #pragma unroll
    for (int s = 32; s > 0; s >>= 1) {
        ldB += __shfl_down(ldB, s);
        ldM += __shfl_down(ldM, s);
        q   += __shfl_down(q, s);
    }
    if ((tid & 63) == 0) {
        const int w = tid >> 6;
        redsm[0][w] = ldB; redsm[1][w] = ldM; redsm[2][w] = q;
    }
    __syncthreads();
    if (tid == 0) {
        double LB = 0, LM = 0, Q = 0;
        #pragma unroll
        for (int w = 0; w < 4; ++w) { LB += redsm[0][w]; LM += redsm[1][w]; Q += redsm[2][w]; }
        const double sumyy = yy[0] + yy[1] + yy[2] + yy[3];
        const double quad = (sumyy - Q) / noise;
        const double logdetA = (double)(N_PTS - MPIV) * log(noise) + LM - LB;
        const double lml = 0.5 * quad + 0.5 * logdetA
                         + 0.5 * (double)nin[0] * 1.8378770664093453; // log(2*pi)
        out[0] = (float)lml;
    }
}

extern "C" void kernel_launch(void* const* d_in, const int* in_sizes, int n_in,
                              void* d_out, int out_size, void* d_ws, size_t ws_size,
                              hipStream_t stream) {
    const float* traj = (const float*)d_in[0];   // [4, 4096]
    const float* t    = (const float*)d_in[1];   // [4096] sorted
    const float* thf  = (const float*)d_in[2];
    const float* thl  = (const float*)d_in[3];
    const float* thn  = (const float*)d_in[4];
    const int*   nn   = (const int*)d_in[5];
    float* out = (float*)d_out;

    // ws layout: G (96*96 d) | b (96*4 d) | yy (4 d)  -- contiguous fp64
    double* G  = (double*)d_ws;
    double* b  = G + MPIV * MPIV;
    double* yy = b + MPIV * 4;

    zero_kernel<<<16, 256, 0, stream>>>(G);
    gram_fused_kernel<<<NSEG, 256, 0, stream>>>(t, traj, thf, thl, G, b, yy);
    final_kernel<<<1, 256, 0, stream>>>(t, thf, thl, thn, nn, G, b, yy, out);
}

// Round 5
// 234.590 us; speedup vs baseline: 2.7261x; 1.5815x over previous
//
#include <hip/hip_runtime.h>
#include <math.h>

#define N_PTS 4096
#define NSEG  32
#define SEG   128            // N_PTS / NSEG
#define NFREQ 23             // harmonics 1..23
#define FDIM  48             // 1 DC + 2*23 cos/sin + 1 zero pad
#define GSZ   (FDIM * FDIM)  // 2304
#define GP_JITTER 3e-7

// ---------------------------------------------------------------------------
// Kernel 1: deterministic Fourier features Phi (N x 48, built on the fly in
// LDS, fp64 recurrence -> fp32 store), per-segment partials of
//   G = Phi^T Phi (fp64 acc of the STORED fp32 Phi -> PSD-exact),
//   b = Phi^T y  (fp64),  yy = ||y||^2 (fp64).
// K(s,t) = tf*exp(-(s-t)^2/(2 l^2)) ~= sum_m c_m cos(m h (s-t)), trapezoid
// of Bochner integral; alias/truncation both exp(-32) with h = 2pi/(dmax+8/l).
// ---------------------------------------------------------------------------
__global__ __launch_bounds__(256) void gram_kernel(
    const float* __restrict__ t, const float* __restrict__ traj,
    const float* __restrict__ thf, const float* __restrict__ thl,
    double* __restrict__ Gpart, double* __restrict__ bpart,
    double* __restrict__ yypart)
{
    __shared__ float  sPhi[FDIM][SEG + 4];   // 48 x 132 fp32 = 25.3 KB
    __shared__ float  sy[4][SEG];
    __shared__ double sw[NFREQ + 1];

    const int seg = blockIdx.x, tid = threadIdx.x;
    const int ibase = seg * SEG;

    const double tf  = (double)thf[0];
    const double ell = fabs((double)thl[0]);
    const double t0g = (double)t[0], tNg = (double)t[N_PTS - 1];
    const double h   = 6.283185307179586 / ((tNg - t0g) + 8.0 / ell);
    const double pc  = ell * 0.3989422804014327;   // ell / sqrt(2*pi)

    if (tid <= NFREQ) {
        const double om = h * (double)tid;
        const double w  = (tid == 0) ? tf * h * pc
                        : 2.0 * tf * h * pc * exp(-0.5 * ell * ell * om * om);
        sw[tid] = sqrt(w);
    }
    for (int l = tid; l < 4 * SEG; l += 256) {
        const int d = l >> 7, ii = l & (SEG - 1);
        sy[d][ii] = traj[d * N_PTS + ibase + ii];
    }
    __syncthreads();

    // ---- build Phi rows for this segment: thread = point ----
    if (tid < SEG) {
        const double tt = (double)t[ibase + tid];
        double s1, c1;
        sincos(h * tt, &s1, &c1);
        sPhi[0][tid] = (float)sw[0];           // DC: cos(0)=1
        double cm = c1, sm = s1;
        sPhi[1][tid] = (float)(sw[1] * cm);
        sPhi[2][tid] = (float)(sw[1] * sm);
        #pragma unroll
        for (int m = 2; m <= NFREQ; ++m) {     // angle-addition recurrence
            const double cn = cm * c1 - sm * s1;
            const double sn = sm * c1 + cm * s1;
            cm = cn; sm = sn;
            sPhi[2 * m - 1][tid] = (float)(sw[m] * cm);
            sPhi[2 * m][tid]     = (float)(sw[m] * sm);
        }
        sPhi[FDIM - 1][tid] = 0.0f;            // zero pad column (exact)
    }
    __syncthreads();

    // ---- G tile: 16x16 threads, 3x3 register tile, K blocked by 4 ----
    const int ta = tid >> 4, tb = tid & 15;
    const int a0 = 3 * ta, b0 = 3 * tb;
    double acc[3][3];
    #pragma unroll
    for (int d = 0; d < 3; ++d)
        #pragma unroll
        for (int e = 0; e < 3; ++e) acc[d][e] = 0.0;

    for (int q = 0; q < SEG; q += 4) {
        float va[3][4], vb[3][4];
        #pragma unroll
        for (int d = 0; d < 3; ++d) {
            const float4 v = *(const float4*)&sPhi[a0 + d][q];
            va[d][0] = v.x; va[d][1] = v.y; va[d][2] = v.z; va[d][3] = v.w;
            const float4 u = *(const float4*)&sPhi[b0 + d][q];
            vb[d][0] = u.x; vb[d][1] = u.y; vb[d][2] = u.z; vb[d][3] = u.w;
        }
        #pragma unroll
        for (int d = 0; d < 3; ++d)
            #pragma unroll
            for (int e = 0; e < 3; ++e)
                #pragma unroll
                for (int kk = 0; kk < 4; ++kk)
                    acc[d][e] += (double)va[d][kk] * (double)vb[e][kk];
    }
    double* gp = Gpart + (size_t)seg * GSZ;
    #pragma unroll
    for (int d = 0; d < 3; ++d)
        #pragma unroll
        for (int e = 0; e < 3; ++e)
            gp[(a0 + d) * FDIM + (b0 + e)] = acc[d][e];

    // ---- b and yy partials ----
    if (tid < FDIM * 4) {
        const int f = tid >> 2, d = tid & 3;
        double s = 0.0;
        for (int q = 0; q < SEG; q += 4) {
            const float4 p = *(const float4*)&sPhi[f][q];
            const float4 yv = *(const float4*)&sy[d][q];
            s += (double)p.x * (double)yv.x + (double)p.y * (double)yv.y
               + (double)p.z * (double)yv.z + (double)p.w * (double)yv.w;
        }
        bpart[(size_t)seg * FDIM * 4 + tid] = s;
    } else if (tid < FDIM * 4 + 4) {
        const int d = tid - FDIM * 4;
        double s = 0.0;
        for (int q = 0; q < SEG; q += 4) {
            const float4 yv = *(const float4*)&sy[d][q];
            s += (double)yv.x * (double)yv.x + (double)yv.y * (double)yv.y
               + (double)yv.z * (double)yv.z + (double)yv.w * (double)yv.w;
        }
        yypart[seg * 4 + d] = s;
    }
}

// ---------------------------------------------------------------------------
// Kernel 2: reduce partials -> M = noise I + G in LDS, then ONE WAVE does the
// whole 48x48 fp64 Cholesky + forward solve IN REGISTERS via __shfl
// (lane i = row i, all loops compile-time unrolled -> no LDS, no barriers).
//  lml = 0.5*(yy - ||u||^2)/noise + 0.5*[(N-48)log(noise)+logdet(M)]
//        + 0.5*n*log(2pi)
// ---------------------------------------------------------------------------
__global__ __launch_bounds__(256) void final_kernel(
    const double* __restrict__ Gpart, const double* __restrict__ bpart,
    const double* __restrict__ yypart, const float* __restrict__ thn,
    const int* __restrict__ nin, float* __restrict__ out)
{
    __shared__ double sM[FDIM][FDIM + 1];   // 18.8 KB
    __shared__ double sb[FDIM * 4];
    __shared__ double syy[4];

    const int tid = threadIdx.x;
    const double tn = (double)thn[0];
    const double noise = GP_JITTER + tn * tn;

    // ---- phase A: fold NSEG partials (all 256 threads) ----
    for (int e = tid; e < GSZ; e += 256) {
        double s = 0.0;
        #pragma unroll 8
        for (int sg = 0; sg < NSEG; ++sg) s += Gpart[(size_t)sg * GSZ + e];
        const int i = e / FDIM, j = e - i * FDIM;
        sM[i][j] = s + (i == j ? noise : 0.0);
    }
    if (tid < FDIM * 4) {
        double s = 0.0;
        #pragma unroll 8
        for (int sg = 0; sg < NSEG; ++sg) s += bpart[(size_t)sg * FDIM * 4 + tid];
        sb[tid] = s;
    } else if (tid < FDIM * 4 + 4) {
        const int d = tid - FDIM * 4;
        double s = 0.0;
        for (int sg = 0; sg < NSEG; ++sg) s += yypart[sg * 4 + d];
        syy[d] = s;
    }
    __syncthreads();

    // ---- phase B: single-wave register Cholesky + solve ----
    if (tid < 64) {
        const int i = tid;
        const bool act = (i < FDIM);
        double a[FDIM];
        #pragma unroll
        for (int j = 0; j < FDIM; ++j) a[j] = act ? sM[i][j] : 0.0;

        const double dfloor = 1e-6 * noise;   // graceful guard (never expected)
        double ld = 0.0, myinv = 0.0;
        #pragma unroll
        for (int j = 0; j < FDIM; ++j) {
            double diag = __shfl(a[j], j);            // updated M[j][j]
            diag = fmax(diag, dfloor);
            const double s = sqrt(diag);
            const double inv = 1.0 / s;
            if (i == j) { ld = 2.0 * log(s); myinv = inv; }
            const double lij = a[j] * inv;            // L[i][j], valid i>=j
            a[j] = lij;
            #pragma unroll
            for (int k = j + 1; k < FDIM; ++k)
                a[k] -= lij * __shfl(lij, k);         // rank-1 trailing update
        }

        // forward solve L u = b, 4 RHS, q = ||u||^2 collected at lane j
        double b0 = act ? sb[i * 4 + 0] : 0.0;
        double b1 = act ? sb[i * 4 + 1] : 0.0;
        double b2 = act ? sb[i * 4 + 2] : 0.0;
        double b3 = act ? sb[i * 4 + 3] : 0.0;
        double ac0 = 0.0, ac1 = 0.0, ac2 = 0.0, ac3 = 0.0, q = 0.0;
        #pragma unroll
        for (int j = 0; j < FDIM; ++j) {
            const double invj = __shfl(myinv, j);
            const double u0 = __shfl(b0 - ac0, j) * invj;
            const double u1 = __shfl(b1 - ac1, j) * invj;
            const double u2 = __shfl(b2 - ac2, j) * invj;
            const double u3 = __shfl(b3 - ac3, j) * invj;
            if (i == j) q = u0 * u0 + u1 * u1 + u2 * u2 + u3 * u3;
            ac0 += a[j] * u0; ac1 += a[j] * u1;
            ac2 += a[j] * u2; ac3 += a[j] * u3;
        }

        // wave reduction of ld and q
        #pragma unroll
        for (int s = 32; s > 0; s >>= 1) {
            ld += __shfl_down(ld, s);
            q  += __shfl_down(q, s);
        }
        if (tid == 0) {
            const double sumyy = syy[0] + syy[1] + syy[2] + syy[3];
            const double quad = (sumyy - q) / noise;
            const double logdetA = (double)(N_PTS - FDIM) * log(noise) + ld;
            const double lml = 0.5 * quad + 0.5 * logdetA
                             + 0.5 * (double)nin[0] * 1.8378770664093453;
            out[0] = (float)lml;
        }
    }
}

extern "C" void kernel_launch(void* const* d_in, const int* in_sizes, int n_in,
                              void* d_out, int out_size, void* d_ws, size_t ws_size,
                              hipStream_t stream) {
    const float* traj = (const float*)d_in[0];   // [4, 4096]
    const float* t    = (const float*)d_in[1];   // [4096] sorted
    const float* thf  = (const float*)d_in[2];
    const float* thl  = (const float*)d_in[3];
    const float* thn  = (const float*)d_in[4];
    const int*   nn   = (const int*)d_in[5];
    float* out = (float*)d_out;

    // ws: Gpart (32*2304 d) | bpart (32*192 d) | yypart (32*4 d)  ~ 640 KB
    double* Gpart  = (double*)d_ws;
    double* bpart  = Gpart + (size_t)NSEG * GSZ;
    double* yypart = bpart + (size_t)NSEG * FDIM * 4;

    gram_kernel<<<NSEG, 256, 0, stream>>>(t, traj, thf, thl, Gpart, bpart, yypart);
    final_kernel<<<1, 256, 0, stream>>>(Gpart, bpart, yypart, thn, nn, out);
}

// Round 6
// 147.080 us; speedup vs baseline: 4.3480x; 1.5950x over previous
//
#include <hip/hip_runtime.h>
#include <math.h>

#define N_PTS 4096
#define NSEG  32
#define SEG   128            // N_PTS / NSEG
#define NFREQ 23             // harmonics 1..23
#define FDIM  48             // 1 DC + 2*23 cos/sin + 1 zero pad
#define GSZ   (FDIM * FDIM)  // 2304
#define GP_JITTER 3e-7

// ---------------------------------------------------------------------------
// Kernel 1: deterministic Fourier features Phi (N x 48, built on the fly in
// LDS, fp64 recurrence -> fp32 store), per-segment partials of
//   G = Phi^T Phi (fp64 acc of the STORED fp32 Phi -> PSD-exact),
//   b = Phi^T y  (fp64),  yy = ||y||^2 (fp64).
// K(s,t) = tf*exp(-(s-t)^2/(2 l^2)) ~= sum_m c_m cos(m h (s-t)), trapezoid
// of Bochner integral; alias/truncation both exp(-32) with h = 2pi/(dmax+8/l).
// ---------------------------------------------------------------------------
__global__ __launch_bounds__(256) void gram_kernel(
    const float* __restrict__ t, const float* __restrict__ traj,
    const float* __restrict__ thf, const float* __restrict__ thl,
    double* __restrict__ Gpart, double* __restrict__ bpart,
    double* __restrict__ yypart)
{
    __shared__ float  sPhi[FDIM][SEG + 4];   // 48 x 132 fp32 = 25.3 KB
    __shared__ float  sy[4][SEG];
    __shared__ double sw[NFREQ + 1];

    const int seg = blockIdx.x, tid = threadIdx.x;
    const int ibase = seg * SEG;

    const double tf  = (double)thf[0];
    const double ell = fabs((double)thl[0]);
    const double t0g = (double)t[0], tNg = (double)t[N_PTS - 1];
    const double h   = 6.283185307179586 / ((tNg - t0g) + 8.0 / ell);
    const double pc  = ell * 0.3989422804014327;   // ell / sqrt(2*pi)

    if (tid <= NFREQ) {
        const double om = h * (double)tid;
        const double w  = (tid == 0) ? tf * h * pc
                        : 2.0 * tf * h * pc * exp(-0.5 * ell * ell * om * om);
        sw[tid] = sqrt(w);
    }
    for (int l = tid; l < 4 * SEG; l += 256) {
        const int d = l >> 7, ii = l & (SEG - 1);
        sy[d][ii] = traj[d * N_PTS + ibase + ii];
    }
    __syncthreads();

    // ---- build Phi rows for this segment: thread = point ----
    if (tid < SEG) {
        const double tt = (double)t[ibase + tid];
        double s1, c1;
        sincos(h * tt, &s1, &c1);
        sPhi[0][tid] = (float)sw[0];           // DC: cos(0)=1
        double cm = c1, sm = s1;
        sPhi[1][tid] = (float)(sw[1] * cm);
        sPhi[2][tid] = (float)(sw[1] * sm);
        #pragma unroll
        for (int m = 2; m <= NFREQ; ++m) {     // angle-addition recurrence
            const double cn = cm * c1 - sm * s1;
            const double sn = sm * c1 + cm * s1;
            cm = cn; sm = sn;
            sPhi[2 * m - 1][tid] = (float)(sw[m] * cm);
            sPhi[2 * m][tid]     = (float)(sw[m] * sm);
        }
        sPhi[FDIM - 1][tid] = 0.0f;            // zero pad column (exact)
    }
    __syncthreads();

    // ---- G tile: 16x16 threads, 3x3 register tile, K blocked by 4 ----
    const int ta = tid >> 4, tb = tid & 15;
    const int a0 = 3 * ta, b0 = 3 * tb;
    double acc[3][3];
    #pragma unroll
    for (int d = 0; d < 3; ++d)
        #pragma unroll
        for (int e = 0; e < 3; ++e) acc[d][e] = 0.0;

    for (int q = 0; q < SEG; q += 4) {
        float va[3][4], vb[3][4];
        #pragma unroll
        for (int d = 0; d < 3; ++d) {
            const float4 v = *(const float4*)&sPhi[a0 + d][q];
            va[d][0] = v.x; va[d][1] = v.y; va[d][2] = v.z; va[d][3] = v.w;
            const float4 u = *(const float4*)&sPhi[b0 + d][q];
            vb[d][0] = u.x; vb[d][1] = u.y; vb[d][2] = u.z; vb[d][3] = u.w;
        }
        #pragma unroll
        for (int d = 0; d < 3; ++d)
            #pragma unroll
            for (int e = 0; e < 3; ++e)
                #pragma unroll
                for (int kk = 0; kk < 4; ++kk)
                    acc[d][e] += (double)va[d][kk] * (double)vb[e][kk];
    }
    double* gp = Gpart + (size_t)seg * GSZ;
    #pragma unroll
    for (int d = 0; d < 3; ++d)
        #pragma unroll
        for (int e = 0; e < 3; ++e)
            gp[(a0 + d) * FDIM + (b0 + e)] = acc[d][e];

    // ---- b and yy partials ----
    if (tid < FDIM * 4) {
        const int f = tid >> 2, d = tid & 3;
        double s = 0.0;
        for (int q = 0; q < SEG; q += 4) {
            const float4 p = *(const float4*)&sPhi[f][q];
            const float4 yv = *(const float4*)&sy[d][q];
            s += (double)p.x * (double)yv.x + (double)p.y * (double)yv.y
               + (double)p.z * (double)yv.z + (double)p.w * (double)yv.w;
        }
        bpart[(size_t)seg * FDIM * 4 + tid] = s;
    } else if (tid < FDIM * 4 + 4) {
        const int d = tid - FDIM * 4;
        double s = 0.0;
        for (int q = 0; q < SEG; q += 4) {
            const float4 yv = *(const float4*)&sy[d][q];
            s += (double)yv.x * (double)yv.x + (double)yv.y * (double)yv.y
               + (double)yv.z * (double)yv.z + (double)yv.w * (double)yv.w;
        }
        yypart[seg * 4 + d] = s;
    }
}

// ---------------------------------------------------------------------------
// Kernel 2: reduce partials -> M = noise I + G held as 9 REGISTER elements
// per thread (2304 = 9*256, coords fixed per thread -> no dynamic indexing,
// no spill). Distributed Cholesky: per column, diag owner -> barrier ->
// column owners scale + publish to LDS colbuf (+persist L) -> barrier ->
// all threads rank-1 update their 9 register elements. log() kept OFF the
// serial chain. Forward solve on wave 0 via shuffles reading L from LDS.
// ---------------------------------------------------------------------------
__global__ __launch_bounds__(256) void final_kernel(
    const double* __restrict__ Gpart, const double* __restrict__ bpart,
    const double* __restrict__ yypart, const float* __restrict__ thn,
    const int* __restrict__ nin, float* __restrict__ out)
{
    __shared__ double sL[FDIM][FDIM + 1];   // 18.4 KB
    __shared__ double sdinv[FDIM];
    __shared__ double colbuf[FDIM];
    __shared__ double sb[FDIM * 4];
    __shared__ double syy[4];

    const int tid = threadIdx.x;
    const double tn = (double)thn[0];
    const double noise = GP_JITTER + tn * tn;

    // ---- fold NSEG partials straight into the 9 register elements ----
    int ie[9], ke[9];
    double m[9];
    #pragma unroll
    for (int r = 0; r < 9; ++r) {
        const int e = r * 256 + tid;
        ie[r] = e / FDIM;
        ke[r] = e - ie[r] * FDIM;
        double s = 0.0;
        #pragma unroll 8
        for (int sg = 0; sg < NSEG; ++sg)
            s += Gpart[(size_t)sg * GSZ + e];
        m[r] = s + ((ie[r] == ke[r]) ? noise : 0.0);
    }
    if (tid < FDIM * 4) {
        double s = 0.0;
        #pragma unroll 8
        for (int sg = 0; sg < NSEG; ++sg) s += bpart[(size_t)sg * FDIM * 4 + tid];
        sb[tid] = s;
    } else if (tid < FDIM * 4 + 4) {
        const int d = tid - FDIM * 4;
        double s = 0.0;
        for (int sg = 0; sg < NSEG; ++sg) s += yypart[sg * 4 + d];
        syy[d] = s;
    }
    __syncthreads();

    // ---- distributed Cholesky, 2 barriers per column ----
    const double dfloor = 1e-6 * noise;   // graceful guard (never expected)
    for (int j = 0; j < FDIM; ++j) {
        #pragma unroll
        for (int r = 0; r < 9; ++r)
            if (ie[r] == j && ke[r] == j) {           // exactly one thread
                const double s = sqrt(fmax(m[r], dfloor));
                sL[j][j] = s;
                sdinv[j] = 1.0 / s;
            }
        __syncthreads();
        const double inv = sdinv[j];                  // LDS broadcast
        #pragma unroll
        for (int r = 0; r < 9; ++r)
            if (ke[r] == j && ie[r] > j) {
                const double lij = m[r] * inv;
                m[r] = lij;
                colbuf[ie[r]] = lij;
                sL[ie[r]][j] = lij;
            }
        __syncthreads();
        #pragma unroll
        for (int r = 0; r < 9; ++r)
            if (ie[r] > j && ke[r] > j)
                m[r] -= colbuf[ie[r]] * colbuf[ke[r]];
        // no barrier: next P1 writes sdinv[j+1]/sL[j+1][j+1] (disjoint from
        // colbuf); P2(j+1) is fenced from this P3 by the first barrier above.
    }
    __syncthreads();

    // ---- wave 0: forward solve L u = b (4 RHS), logdet, assembly ----
    if (tid < 64) {
        const int i = tid;
        const bool act = (i < FDIM);
        double r0 = act ? sb[i * 4 + 0] : 0.0;
        double r1 = act ? sb[i * 4 + 1] : 0.0;
        double r2 = act ? sb[i * 4 + 2] : 0.0;
        double r3 = act ? sb[i * 4 + 3] : 0.0;
        const double linv = act ? sdinv[i] : 0.0;
        double q = 0.0;
        for (int j = 0; j < FDIM; ++j) {
            const double invj = __shfl(linv, j);
            const double u0 = __shfl(r0 * invj, j);   // true u_j from lane j
            const double u1 = __shfl(r1 * invj, j);
            const double u2 = __shfl(r2 * invj, j);
            const double u3 = __shfl(r3 * invj, j);
            if (i == j) q = u0 * u0 + u1 * u1 + u2 * u2 + u3 * u3;
            const double lij = (act && i > j) ? sL[i][j] : 0.0;
            r0 -= lij * u0; r1 -= lij * u1; r2 -= lij * u2; r3 -= lij * u3;
        }
        double ldv = act ? 2.0 * log(sL[i][i]) : 0.0;  // off the serial chain
        #pragma unroll
        for (int s = 32; s > 0; s >>= 1) {
            q   += __shfl_down(q, s);
            ldv += __shfl_down(ldv, s);
        }
        if (tid == 0) {
            const double sumyy = syy[0] + syy[1] + syy[2] + syy[3];
            const double quad = (sumyy - q) / noise;
            const double logdetA = (double)(N_PTS - FDIM) * log(noise) + ldv;
            const double lml = 0.5 * quad + 0.5 * logdetA
                             + 0.5 * (double)nin[0] * 1.8378770664093453;
            out[0] = (float)lml;
        }
    }
}

extern "C" void kernel_launch(void* const* d_in, const int* in_sizes, int n_in,
                              void* d_out, int out_size, void* d_ws, size_t ws_size,
                              hipStream_t stream) {
    const float* traj = (const float*)d_in[0];   // [4, 4096]
    const float* t    = (const float*)d_in[1];   // [4096] sorted
    const float* thf  = (const float*)d_in[2];
    const float* thl  = (const float*)d_in[3];
    const float* thn  = (const float*)d_in[4];
    const int*   nn   = (const int*)d_in[5];
    float* out = (float*)d_out;

    // ws: Gpart (32*2304 d) | bpart (32*192 d) | yypart (32*4 d)  ~ 640 KB
    double* Gpart  = (double*)d_ws;
    double* bpart  = Gpart + (size_t)NSEG * GSZ;
    double* yypart = bpart + (size_t)NSEG * FDIM * 4;

    gram_kernel<<<NSEG, 256, 0, stream>>>(t, traj, thf, thl, Gpart, bpart, yypart);
    final_kernel<<<1, 256, 0, stream>>>(Gpart, bpart, yypart, thn, nn, out);
}